// Round 1
// baseline (103.444 us; speedup 1.0000x reference)
//
#include <hip/hip_runtime.h>

// LNCC loss, shape (4,1,128,128,128) f32.
// scales=[32,64] w=[0.4,0.6], steps=[16,32], dilation=2.
// Only even (d,h,w) coords are sampled => work on the 64^3 even-subsampled
// volume. Windows: ksz=32 -> len 32 stride 8 (5 per dim); ksz=64 -> full sum.
// Chunk decomposition: 8^3 chunks of 8^3 even voxels; window = 4x4x4 chunks.

#define NSTAT 5  // 0:x 1:y 2:x2 3:y2 4:xy

__global__ __launch_bounds__(256) void lncc_pass1(
    const float* __restrict__ x, const float* __restrict__ y,
    float* __restrict__ chunks /* [4][512][5] */) {
  const int blk = blockIdx.x;          // 256 blocks: b*64 + ci*8 + cj
  const int b  = blk >> 6;
  const int ci = (blk >> 3) & 7;
  const int cj = blk & 7;
  const int tid = threadIdx.x;
  const int w4 = tid & 31;             // float4 index along w (covers w=4*w4..+3)
  const int s  = tid >> 5;             // 0..7 -> even-h row within chunk
  const size_t base = (size_t)b * (128u * 128u * 128u)
                    + (size_t)(16 * cj + 2 * s) * 128 + (size_t)w4 * 4;

  float sx = 0.f, sy = 0.f, sx2 = 0.f, sy2 = 0.f, sxy = 0.f;
#pragma unroll
  for (int i = 0; i < 8; ++i) {        // even-d rows: d = 16*ci + 2*i
    size_t off = base + (size_t)(16 * ci + 2 * i) * (128 * 128);
    float4 a = *(const float4*)(x + off);
    float4 t = *(const float4*)(y + off);
    // even w elements are .x (w=4*w4) and .z (w=4*w4+2); both in chunk ck=w4/4
    sx  += a.x + a.z;
    sy  += t.x + t.z;
    sx2 += a.x * a.x + a.z * a.z;
    sy2 += t.x * t.x + t.z * t.z;
    sxy += a.x * t.x + a.z * t.z;
  }

  __shared__ float sd[256 * NSTAT];
  sd[tid]        = sx;
  sd[256 + tid]  = sy;
  sd[512 + tid]  = sx2;
  sd[768 + tid]  = sy2;
  sd[1024 + tid] = sxy;
  __syncthreads();

  // 40 threads finalize: stat k = tid/8, ck = tid%8.
  // Threads belonging to ck are tid' = sdi*32 + ck*4 + j (sdi<8, j<4).
  if (tid < 40) {
    const int k = tid >> 3, ck = tid & 7;
    float acc = 0.f;
#pragma unroll
    for (int sdi = 0; sdi < 8; ++sdi)
#pragma unroll
      for (int j = 0; j < 4; ++j)
        acc += sd[k * 256 + sdi * 32 + ck * 4 + j];
    const int c = ci * 64 + cj * 8 + ck;
    chunks[((size_t)b * 512 + c) * NSTAT + k] = acc;
  }
}

__global__ __launch_bounds__(512) void lncc_pass2(
    const float* __restrict__ chunks, float* __restrict__ out) {
  const int tid = threadIdx.x;
  __shared__ float s5[2048 * NSTAT];  // 40 KB: [(b*512 + c)*5 + k]
  for (int i = tid; i < 2048 * NSTAT; i += 512) s5[i] = chunks[i];
  __syncthreads();

  // ---- per-batch totals (ksz=64 scale): reduce 512 chunks x 5 stats ----
  __shared__ double part[8 * NSTAT];
  __shared__ double totl[4 * NSTAT];
  for (int b = 0; b < 4; ++b) {
    double vv[NSTAT];
    const int cbase = (b * 512 + tid) * NSTAT;
#pragma unroll
    for (int k = 0; k < NSTAT; ++k) vv[k] = (double)s5[cbase + k];
#pragma unroll
    for (int off = 32; off; off >>= 1)
#pragma unroll
      for (int k = 0; k < NSTAT; ++k) vv[k] += __shfl_down(vv[k], off);
    if ((tid & 63) == 0)
#pragma unroll
      for (int k = 0; k < NSTAT; ++k) part[(tid >> 6) * NSTAT + k] = vv[k];
    __syncthreads();
    if (tid < NSTAT) {
      double sum = 0.0;
      for (int w = 0; w < 8; ++w) sum += part[w * NSTAT + tid];
      totl[b * NSTAT + tid] = sum;
    }
    __syncthreads();
  }

  // ---- ksz=32 windows: 500 of them, each sums 4x4x4 chunks ----
  double lncc = 0.0;
  if (tid < 500) {
    const int b = tid / 125, rem = tid % 125;
    const int od = rem / 25, oh = (rem / 5) % 5, ow = rem % 5;
    double a0 = 0, a1 = 0, a2 = 0, a3 = 0, a4 = 0;
    for (int ci = od; ci < od + 4; ++ci)
      for (int cj = oh; cj < oh + 4; ++cj)
        for (int ck = ow; ck < ow + 4; ++ck) {
          const int idx = (b * 512 + ci * 64 + cj * 8 + ck) * NSTAT;
          a0 += s5[idx];     a1 += s5[idx + 1];
          a2 += s5[idx + 2]; a3 += s5[idx + 3];
          a4 += s5[idx + 4];
        }
    const double numel = 32768.0;  // 32^3
    const double cross = a4 - a0 * a1 / numel;
    const double xvar  = a2 - a0 * a0 / numel;
    const double yvar  = a3 - a1 * a1 / numel;
    lncc = cross * cross / (xvar * yvar + 1e-5);
  }
#pragma unroll
  for (int off = 32; off; off >>= 1) lncc += __shfl_down(lncc, off);
  __shared__ double dred[8];
  if ((tid & 63) == 0) dred[tid >> 6] = lncc;
  __syncthreads();

  if (tid == 0) {
    double sum32 = 0.0;
    for (int i = 0; i < 8; ++i) sum32 += dred[i];
    const double mean32 = sum32 / 500.0;
    double sum64 = 0.0;
    for (int b = 0; b < 4; ++b) {
      const double X  = totl[b * NSTAT + 0], Y  = totl[b * NSTAT + 1];
      const double X2 = totl[b * NSTAT + 2], Y2 = totl[b * NSTAT + 3];
      const double XY = totl[b * NSTAT + 4];
      const double numel = 262144.0;  // 64^3
      const double cross = XY - X * Y / numel;
      const double xvar  = X2 - X * X / numel;
      const double yvar  = Y2 - Y * Y / numel;
      sum64 += cross * cross / (xvar * yvar + 1e-5);
    }
    const double mean64 = sum64 * 0.25;
    out[0] = (float)((1.0 - mean32) * 0.4 + (1.0 - mean64) * 0.6);
  }
}

extern "C" void kernel_launch(void* const* d_in, const int* in_sizes, int n_in,
                              void* d_out, int out_size, void* d_ws, size_t ws_size,
                              hipStream_t stream) {
  const float* x = (const float*)d_in[0];
  const float* y = (const float*)d_in[1];
  float* chunks = (float*)d_ws;  // 4*512*5 floats = 40960 B
  lncc_pass1<<<256, 256, 0, stream>>>(x, y, chunks);
  lncc_pass2<<<1, 512, 0, stream>>>(chunks, (float*)d_out);
}